// Round 14
// baseline (508.069 us; speedup 1.0000x reference)
//
#include <hip/hip_runtime.h>
#include <cstdint>

// SplineConv MeshEncoder: 3 layers, K=3 DIM=3 M=27, dims 3->64->64->64.
// R27 = R26 (394.5us; layer64 FROZEN at 88us) + un-profiled-half slimming:
//   layer64 is now 176/394us; the stable ~218us remainder (layer0,
//   basis_sort, count, scans, build_wb2, launch gaps) is the majority.
//   (1) s_w f32 array DELETED: layer0 reads bf16 weights from s_wcol
//       (w = wcol[ec*32 + base + coff], base from meta bits 24-27,
//       coff = lane corner constant). basis_sort stores 77->51MB.
//   (2) 3 scan launches fused into one single-block two-pass scan
//       (1024 thr x 49 elems, no per-thread arrays -> no scratch).
//   (3) layer64 kernel byte-identical to R26.
//   R16: NO LDS atomics. R14: bf16 h. R20: no tr_read.

typedef __attribute__((ext_vector_type(8))) short short8;
typedef __attribute__((ext_vector_type(4))) float floatx4;

#define AS1 __attribute__((address_space(1)))
#define AS3 __attribute__((address_space(3)))

__device__ inline short f2bf(float f) {
    union { float f; unsigned u; } x; x.f = f;
    unsigned r = x.u + 0x7FFF + ((x.u >> 16) & 1);   // round-to-nearest-even
    return (short)(r >> 16);
}

__device__ inline float bf2f(unsigned short u) {
    union { unsigned u; float f; } x;
    x.u = ((unsigned)u) << 16;
    return x.f;
}

// ---------------- preprocessing ----------------

__global__ void count_kernel(const int* __restrict__ ei, int* __restrict__ count, int E) {
    int e = blockIdx.x * blockDim.x + threadIdx.x;
    if (e < E) atomicAdd(&count[ei[E + e]], 1);
}

// Single-block scan: row_ptr = exclusive prefix of count; cursor = copy.
// Two passes over each thread's 49-element strip (no per-thread arrays).
__global__ __launch_bounds__(1024) void scan_full_kernel(const int* __restrict__ count,
                                                         int* __restrict__ row_ptr,
                                                         int* __restrict__ cursor, int N) {
    __shared__ int wsum[16];
    int tid = threadIdx.x, lane = tid & 63, wid = tid >> 6;
    int per = (N + 1023) >> 10;
    int start = tid * per;
    // pass 1: strip sum
    int sum = 0;
    for (int k = 0; k < per; k++) {
        int i = start + k;
        sum += (i < N) ? count[i] : 0;
    }
    // wave inclusive scan of strip sums
    int incl = sum;
#pragma unroll
    for (int off = 1; off < 64; off <<= 1) {
        int t = __shfl_up(incl, off, 64);
        if (lane >= off) incl += t;
    }
    if (lane == 63) wsum[wid] = incl;
    __syncthreads();
    if (tid < 16) {
        int w = wsum[tid];
#pragma unroll
        for (int off = 1; off < 16; off <<= 1) {
            int t = __shfl_up(w, off, 16);
            if ((tid & 15) >= off) w += t;
        }
        wsum[tid] = w;
    }
    __syncthreads();
    int base = ((wid > 0) ? wsum[wid - 1] : 0) + incl - sum;   // exclusive for strip
    // pass 2: write running prefix
    int running = base;
    for (int k = 0; k < per; k++) {
        int i = start + k;
        if (i < N) {
            row_ptr[i] = running;
            cursor[i] = running;
            running += count[i];
        }
    }
    if (tid == 1023) row_ptr[N] = base + sum;
}

// meta = src | base<<24. s_wcol: 32 bf16 A-column per edge
// (row = base+coff(c); rows 27-31 = 0). Used by BOTH layer0 and layer64.
__global__ void basis_sort_kernel(const int* __restrict__ ei, const float* __restrict__ attr,
                                  const int* __restrict__ count, int* __restrict__ cursor,
                                  int* __restrict__ s_meta,
                                  unsigned short* __restrict__ s_wcol, int E) {
    int e = blockIdx.x * blockDim.x + threadIdx.x;
    if (e >= E) return;
    int src = ei[e];
    int dst = ei[E + e];
    float f[3]; int i0[3];
#pragma unroll
    for (int d = 0; d < 3; d++) {
        float pos = attr[e * 3 + d] * 2.0f;          // K-1 = 2
        float fl = floorf(pos);
        fl = fminf(fmaxf(fl, 0.0f), 1.0f);           // clip to [0, K-2]
        i0[d] = (int)fl;
        f[d] = pos - fl;
    }
    int base = i0[0] + 3 * i0[1] + 9 * i0[2];        // in {0,1,3,4,9,10,12,13}
    float invd = 1.0f / fmaxf((float)count[dst], 1.0f);
    int p = atomicAdd(&cursor[dst], 1);
    s_meta[p] = src | (base << 24);
    float w[8];
#pragma unroll
    for (int c = 0; c < 8; c++) {
        float ww = invd;
#pragma unroll
        for (int d = 0; d < 3; d++) {
            int off = (c >> d) & 1;
            ww *= off ? f[d] : (1.0f - f[d]);
        }
        w[c] = ww;
    }
    // A-column: zero 64B record, then scatter 8 bf16 (same line, prog order)
    unsigned short* wc = s_wcol + (size_t)p * 32;
    short8 z8 = {0, 0, 0, 0, 0, 0, 0, 0};
    *(short8*)(wc) = z8;
    *(short8*)(wc + 8) = z8;
    *(short8*)(wc + 16) = z8;
    *(short8*)(wc + 24) = z8;
#pragma unroll
    for (int c = 0; c < 8; c++) {
        int coff = (c & 1) + 3 * ((c >> 1) & 1) + 9 * (c >> 2);
        wc[base + coff] = (unsigned short)f2bf(w[c]);
    }
}

// Pre-swizzle [W(1728,64); Wr(64,64)] into bf16 MFMA B-frag order (R1-proven).
__global__ void build_wb2(const float* __restrict__ Wa, const float* __restrict__ Ra,
                          unsigned short* __restrict__ wba,
                          const float* __restrict__ Wb, const float* __restrict__ Rb,
                          unsigned short* __restrict__ wbb) {
    int idx0 = blockIdx.x * blockDim.x + threadIdx.x;   // [0, 2*4*56*64)
    int half = idx0 / (4 * 56 * 64);
    if (half >= 2) return;
    int idx = idx0 - half * (4 * 56 * 64);
    const float* W = half ? Wb : Wa;
    const float* Wr = half ? Rb : Ra;
    unsigned short* wb = half ? wbb : wba;
    int l = idx & 63;
    int c = (idx >> 6) % 56;
    int t = idx / (56 * 64);
    int q = l >> 4, o = t * 16 + (l & 15);
    short8 out;
#pragma unroll
    for (int j = 0; j < 8; j++) {
        int k = c * 32 + q * 8 + j;
        float v = (k < 1728) ? W[(size_t)k * 64 + o] : Wr[(size_t)(k - 1728) * 64 + o];
        out[j] = f2bf(v);
    }
    *(short8*)(wb + (size_t)idx * 8) = out;
}

// ---------------- layer 0 (CIN=3): dual-edge Phase A, wcol weights ----------------
__global__ __launch_bounds__(256) void layer0_kernel(
    const float* __restrict__ x, const float* __restrict__ W0,
    const float* __restrict__ Wr, const float* __restrict__ bias,
    const int* __restrict__ row_ptr, const int* __restrict__ s_meta,
    const unsigned short* __restrict__ s_wcol, unsigned short* __restrict__ h_out, int N) {
    constexpr int NPB = 32, KT = 84;
    __shared__ __align__(16) float acc[NPB * 2 * KT];   // 21.5 KB (dual copies)
    int tid = threadIdx.x, lane = tid & 63, wv = tid >> 6;
    int n0 = blockIdx.x * NPB;
    for (int k = tid; k < NPB * 2 * KT; k += 256) acc[k] = 0.0f;
    __syncthreads();

    int d = lane >> 5, hl = lane & 31;
    int c = hl / 3, i = hl - c * 3;
    bool act = (hl < 24);
    int cc = act ? c : 0;
    int coff = (cc & 1) + 3 * ((cc >> 1) & 1) + 9 * (cc >> 2);   // corner offset

    for (int g2 = 0; g2 < 8; g2++) {
        int g = wv * 8 + g2;
        int n = n0 + g;
        if (n >= N) continue;
        if (lane < 3) acc[(g * 2) * KT + 81 + lane] = x[(size_t)n * 3 + lane];  // root
        int rs = row_ptr[n], re = row_ptr[n + 1];
        int npairs = (re - rs + 1) >> 1;
        float* accd = &acc[(g * 2 + d) * KT];
        for (int pb = 0; pb < npairs; pb += 4) {
            int metas[4]; float ws_[4], xs_[4];
#pragma unroll
            for (int j = 0; j < 4; j++) {            // clamp invalid -> rs (valid, w=0)
                int ej = rs + (pb + j) * 2 + d;
                bool v = (pb + j < npairs) && (ej < re);
                int ec = v ? ej : rs;
                metas[j] = s_meta[ec];
                int base = (metas[j] >> 24) & 0xF;
                float wv_ = bf2f(s_wcol[(size_t)ec * 32 + base + coff]);
                ws_[j] = v ? wv_ : 0.0f;
            }
#pragma unroll
            for (int j = 0; j < 4; j++)
                xs_[j] = x[(size_t)(metas[j] & 0xFFFFFF) * 3 + i];
#pragma unroll
            for (int j = 0; j < 4; j++) {
                int kidx = ((metas[j] >> 24) & 0xF) + coff;
                if (act) accd[kidx * 3 + i] += ws_[j] * xs_[j];
            }
        }
    }
    __syncthreads();

    // Phase B: o = lane, W in 84 registers; sum the dual acc copies.
    int o = lane;
    float wreg[KT];
#pragma unroll
    for (int k = 0; k < KT; k++)
        wreg[k] = (k < 81) ? W0[k * 64 + o] : Wr[(k - 81) * 64 + o];
    float bv = bias[o];
    for (int g = wv; g < NPB; g += 4) {
        int n = n0 + g;
        if (n >= N) break;
        float s = bv;
#pragma unroll
        for (int k4 = 0; k4 < KT; k4 += 4) {
            floatx4 a0 = *(const floatx4*)&acc[(g * 2) * KT + k4];
            floatx4 a1 = *(const floatx4*)&acc[(g * 2 + 1) * KT + k4];
            s += (a0.x + a1.x) * wreg[k4] + (a0.y + a1.y) * wreg[k4 + 1]
               + (a0.z + a1.z) * wreg[k4 + 2] + (a0.w + a1.w) * wreg[k4 + 3];
        }
        h_out[(size_t)n * 64 + o] = (unsigned short)f2bf(fmaxf(s, 0.0f));
    }
}

// ---------------- 64-ch layers: MFMA Phase A (v6, wcol A-columns) ----------------
// BYTE-IDENTICAL to R26 (FROZEN).
// Per-wave LDS region RGS=3216 shorts (6432B; dword-stride 1608 % 32 = 8):
//   [0..2047]    feat: 32 edges x 64 ch bf16, granule-swizzled
//                (granule G = e*8 + (c3 ^ ((e>>3)<<1)), 8 elems/granule)
//   [2048..3071] wcol: 32 edges x 32 bf16 A-columns (CHUNK level)
//   [3072..3199] meta: 64 ints
//   [0..1791]    acc row (written AFTER the edge loop; aliases feat)
template <bool OUTF32>
__global__ __launch_bounds__(512, 4) void layer64_kernel(
    const unsigned short* __restrict__ h_in, const unsigned short* __restrict__ wb,
    const float* __restrict__ bias, const int* __restrict__ row_ptr,
    const int* __restrict__ s_meta, const unsigned short* __restrict__ s_wcol,
    const unsigned short* __restrict__ zpad, void* __restrict__ h_out, int N) {
    constexpr int NPB = 8;
    constexpr int RGS = 3216;
    __shared__ __align__(16) unsigned short lds[NPB * RGS];   // 51,456 B
    int tid = threadIdx.x, lane = tid & 63;
    int wvu = __builtin_amdgcn_readfirstlane(tid >> 6);   // uniform wave id 0..7
    int n0 = blockIdx.x * NPB;
    int srow = lane & 15, sgrp = lane >> 4;

    unsigned short* reg = &lds[(size_t)wvu * RGS];
    unsigned short* featL = reg;                     // 4096 B
    unsigned short* wcolL = reg + 2048;              // 2048 B (32 edges x 32 bf16)
    int* metaL = (int*)(reg + 3072);                 // 256 B

// stage wcol for 32 window-local edges starting at CB (clamped -> zpad)
#define STAGE_WCOL(CB) do { \
    _Pragma("unroll") for (int k = 0; k < 2; k++) { \
        int el = (CB) + k * 16 + (lane >> 2); \
        const unsigned short* srcp = (el < dw) \
            ? s_wcol + (size_t)(rs + wbo + el) * 32 + (lane & 3) * 8 \
            : zpad + (lane & 3) * 8; \
        __builtin_amdgcn_global_load_lds((const AS1 unsigned int*)srcp, \
            (AS3 unsigned int*)(wcolL + k * 512), 16, 0, 0); \
    } \
} while (0)

    // ---- Phase A: acc(27x64) = Wbasis(27 x deg) X(deg x 64) via MFMA ----
    {
        int n = n0 + wvu;
        if (n >= N) {   // tail hygiene: zero the row so Phase B sees no stale LDS
            for (int k = lane; k < 1792; k += 64) reg[k] = 0;
        } else {
            // zero feat once: unstaged slots stay finite (af=0 covers them)
            {
                short8 z = {0, 0, 0, 0, 0, 0, 0, 0};
#pragma unroll
                for (int s = 0; s < 4; s++)
                    *(short8*)(featL + lane * 8 + s * 512) = z;
            }
            floatx4 facc[2][4];
#pragma unroll
            for (int mt = 0; mt < 2; mt++)
#pragma unroll
                for (int nt = 0; nt < 4; nt++)
                    facc[mt][nt] = (floatx4){0.0f, 0.0f, 0.0f, 0.0f};

            int rs = row_ptr[n], re = row_ptr[n + 1];
            int deg = re - rs;
            for (int wbo = 0; wbo < deg; wbo += 64) {
                int dw = deg - wbo;
                // ---- stage window: meta (64x4B) + wcol chunk0 ----
                __builtin_amdgcn_global_load_lds(
                    (const AS1 unsigned int*)(s_meta + rs + wbo + lane),
                    (AS3 unsigned int*)metaL, 4, 0, 0);
                STAGE_WCOL(0);
                asm volatile("s_waitcnt vmcnt(0)" ::: "memory");   // meta+wcol0 landed
                int vmax = (dw < 64 ? dw : 64) - 1;
                for (int ch2 = 0; ch2 < 2; ch2++) {
                    int cb = ch2 * 32;
                    if (cb >= dw) break;
                    // ---- stage features: exact-count w16 gloads, swizzled src ----
                    //   lane L, instr i: edge el = cb + i*8 + (L>>3),
                    //   granule c3 = (L&7) ^ (i<<1)  (linear dest =>
                    //   granule G = e*8 + (c3 ^ ((e>>3)<<1)))
                    int nsl = dw - cb; if (nsl > 32) nsl = 32;
                    int ngl = (nsl + 7) >> 3;
                    for (int i = 0; i < ngl; i++) {
                        int el = cb + i * 8 + (lane >> 3);
                        if (el > vmax) el = vmax;
                        int ms = metaL[el] & 0xFFFFFF;
                        int c3 = (lane & 7) ^ (i << 1);
                        const unsigned short* srcp = h_in + (size_t)ms * 64 + c3 * 8;
                        __builtin_amdgcn_global_load_lds(
                            (const AS1 unsigned int*)srcp,
                            (AS3 unsigned int*)(featL + i * 512), 16, 0, 0);
                    }
                    // ---- A-frags: 16 ds_read_u16 from wcolL (imm offsets) ----
                    short8 af0, af1;
                    {
                        const unsigned short* wrp = wcolL + (8 * sgrp) * 32 + srow;
#pragma unroll
                        for (int j = 0; j < 8; j++) {
                            af0[j] = (short)wrp[j * 32];
                            af1[j] = (short)wrp[j * 32 + 16];
                        }
                    }
                    // chunk1's wcol reload (single-buffered): only after the
                    // A-build ds_reads completed (WAR guard).
                    if (ch2 == 0 && dw > 32) {
                        asm volatile("s_waitcnt lgkmcnt(0)" ::: "memory");
                        __builtin_amdgcn_sched_barrier(0);
                        STAGE_WCOL(32);
                    }
                    asm volatile("s_waitcnt vmcnt(0)" ::: "memory");   // feat landed
                    // ---- B-frags from swizzled feat + 8 MFMA ----
#pragma unroll
                    for (int nt = 0; nt < 4; nt++) {
                        short8 bn;
#pragma unroll
                        for (int jj = 0; jj < 8; jj++) {
                            int e = sgrp * 8 + jj;           // chunk-local
                            int g = e * 8 + (((nt * 2) + (srow >> 3)) ^ (sgrp << 1));
                            bn[jj] = (short)featL[g * 8 + (srow & 7)];
                        }
                        facc[0][nt] = __builtin_amdgcn_mfma_f32_16x16x32_bf16(
                            af0, bn, facc[0][nt], 0, 0, 0);
                        facc[1][nt] = __builtin_amdgcn_mfma_f32_16x16x32_bf16(
                            af1, bn, facc[1][nt], 0, 0, 0);
                    }
                }
            }
            // ---- C write (layout: col=srow+16nt, row=sgrp*4+r+16mt) ----
#pragma unroll
            for (int mt = 0; mt < 2; mt++)
#pragma unroll
                for (int nt = 0; nt < 4; nt++)
#pragma unroll
                    for (int r = 0; r < 4; r++) {
                        int mrow = mt * 16 + sgrp * 4 + r;
                        if (mrow < 27)
                            reg[mrow * 64 + nt * 16 + srow] =
                                (unsigned short)f2bf(facc[mt][nt][r]);
                    }
            reg[1728 + lane] = h_in[(size_t)n * 64 + lane];   // root row (bf16)
        }
    }
#undef STAGE_WCOL
    __syncthreads();

    // ---- Phase B: 4 waves, each 2 col-groups per A-read ----
    {
        floatx4 f0 = {0.0f, 0.0f, 0.0f, 0.0f};
        floatx4 f1 = {0.0f, 0.0f, 0.0f, 0.0f};
        if (wvu < 4) {
            int hf = wvu >> 1;                   // K half: c in [hf*28, hf*28+28)
            int tp = wvu & 1;                    // col-group pair: nt = 2tp, 2tp+1
            const unsigned short* ap = lds + (size_t)(lane & 7) * RGS + ((lane >> 4) * 8);
            const unsigned short* wbp0 = wb + ((size_t)((tp * 2) * 56) * 64 + lane) * 8;
            const unsigned short* wbp1 = wb + ((size_t)((tp * 2 + 1) * 56) * 64 + lane) * 8;
#pragma unroll
            for (int ci = 0; ci < 28; ci++) {
                int c = hf * 28 + ci;
                short8 af = *(const short8*)(ap + c * 32);
                short8 b0 = *(const short8*)(wbp0 + (size_t)c * 64 * 8);
                short8 b1 = *(const short8*)(wbp1 + (size_t)c * 64 * 8);
                f0 = __builtin_amdgcn_mfma_f32_16x16x32_bf16(af, b0, f0, 0, 0, 0);
                f1 = __builtin_amdgcn_mfma_f32_16x16x32_bf16(af, b1, f1, 0, 0, 0);
            }
        }
        __syncthreads();               // all MFMA reads of lds complete
        if (wvu < 4) {
            float* pfw = (float*)(lds + (size_t)wvu * RGS);
#pragma unroll
            for (int r = 0; r < 4; r++) {
                pfw[r * 64 + lane] = f0[r];
                pfw[256 + r * 64 + lane] = f1[r];
            }
        }
        __syncthreads();
        if (wvu < 4) {
            int t = wvu;                         // output col group t
            int o = t * 16 + (lane & 15);
            float bv = bias[o];
            // producers: hf0 wave (t>>1), hf1 wave (2+(t>>1)); quad (t&1)
            const float* pfA = (const float*)(lds + (size_t)(t >> 1) * RGS)
                             + (t & 1) * 256;
            const float* pfB = (const float*)(lds + (size_t)(2 + (t >> 1)) * RGS)
                             + (t & 1) * 256;
#pragma unroll
            for (int r = 0; r < 4; r++) {
                int m = (lane >> 4) * 4 + r;
                if (m < 8) {
                    int n = n0 + m;
                    if (n < N) {
                        float s = pfA[r * 64 + lane] + pfB[r * 64 + lane];
                        float val = fmaxf(s + bv, 0.0f);
                        if (OUTF32) {
                            ((float*)h_out)[(size_t)n * 64 + o] = val;
                        } else {
                            ((unsigned short*)h_out)[(size_t)n * 64 + o] =
                                (unsigned short)f2bf(val);
                        }
                    }
                }
            }
        }
    }
}

extern "C" void kernel_launch(void* const* d_in, const int* in_sizes, int n_in,
                              void* d_out, int out_size, void* d_ws, size_t ws_size,
                              hipStream_t stream) {
    (void)n_in; (void)out_size; (void)ws_size;
    const float* x    = (const float*)d_in[0];
    const int*   ei   = (const int*)d_in[1];
    const float* attr = (const float*)d_in[2];
    const float* W0 = (const float*)d_in[3];
    const float* R0 = (const float*)d_in[4];
    const float* B0 = (const float*)d_in[5];
    const float* W1 = (const float*)d_in[6];
    const float* R1 = (const float*)d_in[7];
    const float* B1 = (const float*)d_in[8];
    const float* W2 = (const float*)d_in[9];
    const float* R2 = (const float*)d_in[10];
    const float* B2 = (const float*)d_in[11];
    const int N = in_sizes[0] / 3;
    const int E = in_sizes[1] / 2;

    char* ws = (char*)d_ws;
    size_t off = 0;
    auto alloc = [&](size_t bytes) {
        size_t cur = off;
        off = (off + bytes + 255) & ~(size_t)255;
        return cur;
    };
    int* row_ptr = (int*)(ws + alloc((size_t)(N + 1) * 4));
    int* count   = (int*)(ws + alloc((size_t)N * 4));
    int* cursor  = (int*)(ws + alloc((size_t)N * 4));
    unsigned short* zpad = (unsigned short*)(ws + alloc(256));
    int* s_meta  = (int*)(ws + alloc((size_t)E * 4));
    unsigned short* s_wcol = (unsigned short*)(ws + alloc((size_t)E * 32 * 2));
    unsigned short* h_a  = (unsigned short*)(ws + alloc((size_t)N * 64 * 2));
    unsigned short* h_b  = (unsigned short*)(ws + alloc((size_t)N * 64 * 2));
    unsigned short* wb1  = (unsigned short*)(ws + alloc((size_t)4 * 56 * 64 * 8 * 2));
    unsigned short* wb2  = (unsigned short*)(ws + alloc((size_t)4 * 56 * 64 * 8 * 2));

    hipMemsetAsync(count, 0, (size_t)N * 4, stream);
    hipMemsetAsync(zpad, 0, 256, stream);
    count_kernel<<<(E + 255) / 256, 256, 0, stream>>>(ei, count, E);
    scan_full_kernel<<<1, 1024, 0, stream>>>(count, row_ptr, cursor, N);
    basis_sort_kernel<<<(E + 255) / 256, 256, 0, stream>>>(ei, attr, count, cursor,
                                                           s_meta, s_wcol, E);
    build_wb2<<<(2 * 4 * 56 * 64 + 255) / 256, 256, 0, stream>>>(W1, R1, wb1,
                                                                 W2, R2, wb2);

    layer0_kernel<<<(N + 31) / 32, 256, 0, stream>>>(x, W0, R0, B0, row_ptr,
                                                     s_meta, s_wcol, h_a, N);
    layer64_kernel<false><<<(N + 7) / 8, 512, 0, stream>>>(h_a, wb1, B1, row_ptr,
                                                           s_meta, s_wcol, zpad, h_b, N);
    layer64_kernel<true><<<(N + 7) / 8, 512, 0, stream>>>(h_b, wb2, B2, row_ptr,
                                                          s_meta, s_wcol, zpad, d_out, N);
}

// Round 15
// 390.496 us; speedup vs baseline: 1.3011x; 1.3011x over previous
//
#include <hip/hip_runtime.h>
#include <cstdint>

// SplineConv MeshEncoder: 3 layers, K=3 DIM=3 M=27, dims 3->64->64->64.
// R28 = R27 with the scan REVERTED to the R10-proven 3-kernel multi-block
// version. R27's single-block fused scan ran on ONE CU: 125us (0.15% occ),
// +114us total regression -- cleanly isolated by counters. The OTHER R27
// change (s_w f32 deleted; layer0 reads bf16 wcol) PASSED at absmax
// 0.03125 and saved ~4-8us -> kept.
//   layer64 FROZEN at R26 (88us, occ 56%, VGPR 40).
//   R16: NO LDS atomics. R14: bf16 h. R20: no tr_read.

typedef __attribute__((ext_vector_type(8))) short short8;
typedef __attribute__((ext_vector_type(4))) float floatx4;

#define AS1 __attribute__((address_space(1)))
#define AS3 __attribute__((address_space(3)))

__device__ inline short f2bf(float f) {
    union { float f; unsigned u; } x; x.f = f;
    unsigned r = x.u + 0x7FFF + ((x.u >> 16) & 1);   // round-to-nearest-even
    return (short)(r >> 16);
}

__device__ inline float bf2f(unsigned short u) {
    union { unsigned u; float f; } x;
    x.u = ((unsigned)u) << 16;
    return x.f;
}

// ---------------- preprocessing (R10-proven) ----------------

__global__ void count_kernel(const int* __restrict__ ei, int* __restrict__ count, int E) {
    int e = blockIdx.x * blockDim.x + threadIdx.x;
    if (e < E) atomicAdd(&count[ei[E + e]], 1);
}

__global__ __launch_bounds__(1024) void scan_tile_kernel(const int* __restrict__ count,
                                                         int* __restrict__ row_ptr,
                                                         int* __restrict__ bsum, int N) {
    __shared__ int wsum[16];
    int tid = threadIdx.x, lane = tid & 63, wid = tid >> 6;
    int i = blockIdx.x * 1024 + tid;
    int v = (i < N) ? count[i] : 0;
    int incl = v;
#pragma unroll
    for (int off = 1; off < 64; off <<= 1) {
        int t = __shfl_up(incl, off, 64);
        if (lane >= off) incl += t;
    }
    if (lane == 63) wsum[wid] = incl;
    __syncthreads();
    if (tid < 16) {
        int w = wsum[tid];
#pragma unroll
        for (int off = 1; off < 16; off <<= 1) {
            int t = __shfl_up(w, off, 16);
            if ((tid & 15) >= off) w += t;
        }
        wsum[tid] = w;
    }
    __syncthreads();
    int waveoff = (wid > 0) ? wsum[wid - 1] : 0;
    if (i < N) row_ptr[i] = waveoff + incl - v;
    if (tid == 1023) bsum[blockIdx.x] = waveoff + incl;
}

__global__ __launch_bounds__(64) void scan_bsum_kernel(const int* __restrict__ bsum,
                                                       int* __restrict__ boff,
                                                       int* __restrict__ tot, int nb) {
    int tid = threadIdx.x;
    int v = (tid < nb) ? bsum[tid] : 0;
    int incl = v;
#pragma unroll
    for (int off = 1; off < 64; off <<= 1) {
        int t = __shfl_up(incl, off, 64);
        if (tid >= off) incl += t;
    }
    boff[tid] = incl - v;
    if (tid == 63) tot[0] = incl;
}

__global__ __launch_bounds__(1024) void scan_add_kernel(int* __restrict__ row_ptr,
                                                        const int* __restrict__ boff,
                                                        const int* __restrict__ tot,
                                                        int* __restrict__ cursor, int N) {
    int i = blockIdx.x * 1024 + threadIdx.x;
    if (i < N) {
        int r = row_ptr[i] + boff[blockIdx.x];
        row_ptr[i] = r;
        cursor[i] = r;
    }
    if (i == 0) row_ptr[N] = tot[0];
}

// meta = src | base<<24. s_wcol: 32 bf16 A-column per edge
// (row = base+coff(c); rows 27-31 = 0). Used by BOTH layer0 and layer64.
__global__ void basis_sort_kernel(const int* __restrict__ ei, const float* __restrict__ attr,
                                  const int* __restrict__ count, int* __restrict__ cursor,
                                  int* __restrict__ s_meta,
                                  unsigned short* __restrict__ s_wcol, int E) {
    int e = blockIdx.x * blockDim.x + threadIdx.x;
    if (e >= E) return;
    int src = ei[e];
    int dst = ei[E + e];
    float f[3]; int i0[3];
#pragma unroll
    for (int d = 0; d < 3; d++) {
        float pos = attr[e * 3 + d] * 2.0f;          // K-1 = 2
        float fl = floorf(pos);
        fl = fminf(fmaxf(fl, 0.0f), 1.0f);           // clip to [0, K-2]
        i0[d] = (int)fl;
        f[d] = pos - fl;
    }
    int base = i0[0] + 3 * i0[1] + 9 * i0[2];        // in {0,1,3,4,9,10,12,13}
    float invd = 1.0f / fmaxf((float)count[dst], 1.0f);
    int p = atomicAdd(&cursor[dst], 1);
    s_meta[p] = src | (base << 24);
    float w[8];
#pragma unroll
    for (int c = 0; c < 8; c++) {
        float ww = invd;
#pragma unroll
        for (int d = 0; d < 3; d++) {
            int off = (c >> d) & 1;
            ww *= off ? f[d] : (1.0f - f[d]);
        }
        w[c] = ww;
    }
    // A-column: zero 64B record, then scatter 8 bf16 (same line, prog order)
    unsigned short* wc = s_wcol + (size_t)p * 32;
    short8 z8 = {0, 0, 0, 0, 0, 0, 0, 0};
    *(short8*)(wc) = z8;
    *(short8*)(wc + 8) = z8;
    *(short8*)(wc + 16) = z8;
    *(short8*)(wc + 24) = z8;
#pragma unroll
    for (int c = 0; c < 8; c++) {
        int coff = (c & 1) + 3 * ((c >> 1) & 1) + 9 * (c >> 2);
        wc[base + coff] = (unsigned short)f2bf(w[c]);
    }
}

// Pre-swizzle [W(1728,64); Wr(64,64)] into bf16 MFMA B-frag order (R1-proven).
__global__ void build_wb2(const float* __restrict__ Wa, const float* __restrict__ Ra,
                          unsigned short* __restrict__ wba,
                          const float* __restrict__ Wb, const float* __restrict__ Rb,
                          unsigned short* __restrict__ wbb) {
    int idx0 = blockIdx.x * blockDim.x + threadIdx.x;   // [0, 2*4*56*64)
    int half = idx0 / (4 * 56 * 64);
    if (half >= 2) return;
    int idx = idx0 - half * (4 * 56 * 64);
    const float* W = half ? Wb : Wa;
    const float* Wr = half ? Rb : Ra;
    unsigned short* wb = half ? wbb : wba;
    int l = idx & 63;
    int c = (idx >> 6) % 56;
    int t = idx / (56 * 64);
    int q = l >> 4, o = t * 16 + (l & 15);
    short8 out;
#pragma unroll
    for (int j = 0; j < 8; j++) {
        int k = c * 32 + q * 8 + j;
        float v = (k < 1728) ? W[(size_t)k * 64 + o] : Wr[(size_t)(k - 1728) * 64 + o];
        out[j] = f2bf(v);
    }
    *(short8*)(wb + (size_t)idx * 8) = out;
}

// ---------------- layer 0 (CIN=3): dual-edge Phase A, wcol weights ----------------
__global__ __launch_bounds__(256) void layer0_kernel(
    const float* __restrict__ x, const float* __restrict__ W0,
    const float* __restrict__ Wr, const float* __restrict__ bias,
    const int* __restrict__ row_ptr, const int* __restrict__ s_meta,
    const unsigned short* __restrict__ s_wcol, unsigned short* __restrict__ h_out, int N) {
    constexpr int NPB = 32, KT = 84;
    __shared__ __align__(16) float acc[NPB * 2 * KT];   // 21.5 KB (dual copies)
    int tid = threadIdx.x, lane = tid & 63, wv = tid >> 6;
    int n0 = blockIdx.x * NPB;
    for (int k = tid; k < NPB * 2 * KT; k += 256) acc[k] = 0.0f;
    __syncthreads();

    int d = lane >> 5, hl = lane & 31;
    int c = hl / 3, i = hl - c * 3;
    bool act = (hl < 24);
    int cc = act ? c : 0;
    int coff = (cc & 1) + 3 * ((cc >> 1) & 1) + 9 * (cc >> 2);   // corner offset

    for (int g2 = 0; g2 < 8; g2++) {
        int g = wv * 8 + g2;
        int n = n0 + g;
        if (n >= N) continue;
        if (lane < 3) acc[(g * 2) * KT + 81 + lane] = x[(size_t)n * 3 + lane];  // root
        int rs = row_ptr[n], re = row_ptr[n + 1];
        int npairs = (re - rs + 1) >> 1;
        float* accd = &acc[(g * 2 + d) * KT];
        for (int pb = 0; pb < npairs; pb += 4) {
            int metas[4]; float ws_[4], xs_[4];
#pragma unroll
            for (int j = 0; j < 4; j++) {            // clamp invalid -> rs (valid, w=0)
                int ej = rs + (pb + j) * 2 + d;
                bool v = (pb + j < npairs) && (ej < re);
                int ec = v ? ej : rs;
                metas[j] = s_meta[ec];
                int base = (metas[j] >> 24) & 0xF;
                float wv_ = bf2f(s_wcol[(size_t)ec * 32 + base + coff]);
                ws_[j] = v ? wv_ : 0.0f;
            }
#pragma unroll
            for (int j = 0; j < 4; j++)
                xs_[j] = x[(size_t)(metas[j] & 0xFFFFFF) * 3 + i];
#pragma unroll
            for (int j = 0; j < 4; j++) {
                int kidx = ((metas[j] >> 24) & 0xF) + coff;
                if (act) accd[kidx * 3 + i] += ws_[j] * xs_[j];
            }
        }
    }
    __syncthreads();

    // Phase B: o = lane, W in 84 registers; sum the dual acc copies.
    int o = lane;
    float wreg[KT];
#pragma unroll
    for (int k = 0; k < KT; k++)
        wreg[k] = (k < 81) ? W0[k * 64 + o] : Wr[(k - 81) * 64 + o];
    float bv = bias[o];
    for (int g = wv; g < NPB; g += 4) {
        int n = n0 + g;
        if (n >= N) break;
        float s = bv;
#pragma unroll
        for (int k4 = 0; k4 < KT; k4 += 4) {
            floatx4 a0 = *(const floatx4*)&acc[(g * 2) * KT + k4];
            floatx4 a1 = *(const floatx4*)&acc[(g * 2 + 1) * KT + k4];
            s += (a0.x + a1.x) * wreg[k4] + (a0.y + a1.y) * wreg[k4 + 1]
               + (a0.z + a1.z) * wreg[k4 + 2] + (a0.w + a1.w) * wreg[k4 + 3];
        }
        h_out[(size_t)n * 64 + o] = (unsigned short)f2bf(fmaxf(s, 0.0f));
    }
}

// ---------------- 64-ch layers: MFMA Phase A (v6, wcol A-columns) ----------------
// BYTE-IDENTICAL to R26 (FROZEN).
// Per-wave LDS region RGS=3216 shorts (6432B; dword-stride 1608 % 32 = 8):
//   [0..2047]    feat: 32 edges x 64 ch bf16, granule-swizzled
//                (granule G = e*8 + (c3 ^ ((e>>3)<<1)), 8 elems/granule)
//   [2048..3071] wcol: 32 edges x 32 bf16 A-columns (CHUNK level)
//   [3072..3199] meta: 64 ints
//   [0..1791]    acc row (written AFTER the edge loop; aliases feat)
template <bool OUTF32>
__global__ __launch_bounds__(512, 4) void layer64_kernel(
    const unsigned short* __restrict__ h_in, const unsigned short* __restrict__ wb,
    const float* __restrict__ bias, const int* __restrict__ row_ptr,
    const int* __restrict__ s_meta, const unsigned short* __restrict__ s_wcol,
    const unsigned short* __restrict__ zpad, void* __restrict__ h_out, int N) {
    constexpr int NPB = 8;
    constexpr int RGS = 3216;
    __shared__ __align__(16) unsigned short lds[NPB * RGS];   // 51,456 B
    int tid = threadIdx.x, lane = tid & 63;
    int wvu = __builtin_amdgcn_readfirstlane(tid >> 6);   // uniform wave id 0..7
    int n0 = blockIdx.x * NPB;
    int srow = lane & 15, sgrp = lane >> 4;

    unsigned short* reg = &lds[(size_t)wvu * RGS];
    unsigned short* featL = reg;                     // 4096 B
    unsigned short* wcolL = reg + 2048;              // 2048 B (32 edges x 32 bf16)
    int* metaL = (int*)(reg + 3072);                 // 256 B

// stage wcol for 32 window-local edges starting at CB (clamped -> zpad)
#define STAGE_WCOL(CB) do { \
    _Pragma("unroll") for (int k = 0; k < 2; k++) { \
        int el = (CB) + k * 16 + (lane >> 2); \
        const unsigned short* srcp = (el < dw) \
            ? s_wcol + (size_t)(rs + wbo + el) * 32 + (lane & 3) * 8 \
            : zpad + (lane & 3) * 8; \
        __builtin_amdgcn_global_load_lds((const AS1 unsigned int*)srcp, \
            (AS3 unsigned int*)(wcolL + k * 512), 16, 0, 0); \
    } \
} while (0)

    // ---- Phase A: acc(27x64) = Wbasis(27 x deg) X(deg x 64) via MFMA ----
    {
        int n = n0 + wvu;
        if (n >= N) {   // tail hygiene: zero the row so Phase B sees no stale LDS
            for (int k = lane; k < 1792; k += 64) reg[k] = 0;
        } else {
            // zero feat once: unstaged slots stay finite (af=0 covers them)
            {
                short8 z = {0, 0, 0, 0, 0, 0, 0, 0};
#pragma unroll
                for (int s = 0; s < 4; s++)
                    *(short8*)(featL + lane * 8 + s * 512) = z;
            }
            floatx4 facc[2][4];
#pragma unroll
            for (int mt = 0; mt < 2; mt++)
#pragma unroll
                for (int nt = 0; nt < 4; nt++)
                    facc[mt][nt] = (floatx4){0.0f, 0.0f, 0.0f, 0.0f};

            int rs = row_ptr[n], re = row_ptr[n + 1];
            int deg = re - rs;
            for (int wbo = 0; wbo < deg; wbo += 64) {
                int dw = deg - wbo;
                // ---- stage window: meta (64x4B) + wcol chunk0 ----
                __builtin_amdgcn_global_load_lds(
                    (const AS1 unsigned int*)(s_meta + rs + wbo + lane),
                    (AS3 unsigned int*)metaL, 4, 0, 0);
                STAGE_WCOL(0);
                asm volatile("s_waitcnt vmcnt(0)" ::: "memory");   // meta+wcol0 landed
                int vmax = (dw < 64 ? dw : 64) - 1;
                for (int ch2 = 0; ch2 < 2; ch2++) {
                    int cb = ch2 * 32;
                    if (cb >= dw) break;
                    // ---- stage features: exact-count w16 gloads, swizzled src ----
                    //   lane L, instr i: edge el = cb + i*8 + (L>>3),
                    //   granule c3 = (L&7) ^ (i<<1)  (linear dest =>
                    //   granule G = e*8 + (c3 ^ ((e>>3)<<1)))
                    int nsl = dw - cb; if (nsl > 32) nsl = 32;
                    int ngl = (nsl + 7) >> 3;
                    for (int i = 0; i < ngl; i++) {
                        int el = cb + i * 8 + (lane >> 3);
                        if (el > vmax) el = vmax;
                        int ms = metaL[el] & 0xFFFFFF;
                        int c3 = (lane & 7) ^ (i << 1);
                        const unsigned short* srcp = h_in + (size_t)ms * 64 + c3 * 8;
                        __builtin_amdgcn_global_load_lds(
                            (const AS1 unsigned int*)srcp,
                            (AS3 unsigned int*)(featL + i * 512), 16, 0, 0);
                    }
                    // ---- A-frags: 16 ds_read_u16 from wcolL (imm offsets) ----
                    short8 af0, af1;
                    {
                        const unsigned short* wrp = wcolL + (8 * sgrp) * 32 + srow;
#pragma unroll
                        for (int j = 0; j < 8; j++) {
                            af0[j] = (short)wrp[j * 32];
                            af1[j] = (short)wrp[j * 32 + 16];
                        }
                    }
                    // chunk1's wcol reload (single-buffered): only after the
                    // A-build ds_reads completed (WAR guard).
                    if (ch2 == 0 && dw > 32) {
                        asm volatile("s_waitcnt lgkmcnt(0)" ::: "memory");
                        __builtin_amdgcn_sched_barrier(0);
                        STAGE_WCOL(32);
                    }
                    asm volatile("s_waitcnt vmcnt(0)" ::: "memory");   // feat landed
                    // ---- B-frags from swizzled feat + 8 MFMA ----
#pragma unroll
                    for (int nt = 0; nt < 4; nt++) {
                        short8 bn;
#pragma unroll
                        for (int jj = 0; jj < 8; jj++) {
                            int e = sgrp * 8 + jj;           // chunk-local
                            int g = e * 8 + (((nt * 2) + (srow >> 3)) ^ (sgrp << 1));
                            bn[jj] = (short)featL[g * 8 + (srow & 7)];
                        }
                        facc[0][nt] = __builtin_amdgcn_mfma_f32_16x16x32_bf16(
                            af0, bn, facc[0][nt], 0, 0, 0);
                        facc[1][nt] = __builtin_amdgcn_mfma_f32_16x16x32_bf16(
                            af1, bn, facc[1][nt], 0, 0, 0);
                    }
                }
            }
            // ---- C write (layout: col=srow+16nt, row=sgrp*4+r+16mt) ----
#pragma unroll
            for (int mt = 0; mt < 2; mt++)
#pragma unroll
                for (int nt = 0; nt < 4; nt++)
#pragma unroll
                    for (int r = 0; r < 4; r++) {
                        int mrow = mt * 16 + sgrp * 4 + r;
                        if (mrow < 27)
                            reg[mrow * 64 + nt * 16 + srow] =
                                (unsigned short)f2bf(facc[mt][nt][r]);
                    }
            reg[1728 + lane] = h_in[(size_t)n * 64 + lane];   // root row (bf16)
        }
    }
#undef STAGE_WCOL
    __syncthreads();

    // ---- Phase B: 4 waves, each 2 col-groups per A-read ----
    {
        floatx4 f0 = {0.0f, 0.0f, 0.0f, 0.0f};
        floatx4 f1 = {0.0f, 0.0f, 0.0f, 0.0f};
        if (wvu < 4) {
            int hf = wvu >> 1;                   // K half: c in [hf*28, hf*28+28)
            int tp = wvu & 1;                    // col-group pair: nt = 2tp, 2tp+1
            const unsigned short* ap = lds + (size_t)(lane & 7) * RGS + ((lane >> 4) * 8);
            const unsigned short* wbp0 = wb + ((size_t)((tp * 2) * 56) * 64 + lane) * 8;
            const unsigned short* wbp1 = wb + ((size_t)((tp * 2 + 1) * 56) * 64 + lane) * 8;
#pragma unroll
            for (int ci = 0; ci < 28; ci++) {
                int c = hf * 28 + ci;
                short8 af = *(const short8*)(ap + c * 32);
                short8 b0 = *(const short8*)(wbp0 + (size_t)c * 64 * 8);
                short8 b1 = *(const short8*)(wbp1 + (size_t)c * 64 * 8);
                f0 = __builtin_amdgcn_mfma_f32_16x16x32_bf16(af, b0, f0, 0, 0, 0);
                f1 = __builtin_amdgcn_mfma_f32_16x16x32_bf16(af, b1, f1, 0, 0, 0);
            }
        }
        __syncthreads();               // all MFMA reads of lds complete
        if (wvu < 4) {
            float* pfw = (float*)(lds + (size_t)wvu * RGS);
#pragma unroll
            for (int r = 0; r < 4; r++) {
                pfw[r * 64 + lane] = f0[r];
                pfw[256 + r * 64 + lane] = f1[r];
            }
        }
        __syncthreads();
        if (wvu < 4) {
            int t = wvu;                         // output col group t
            int o = t * 16 + (lane & 15);
            float bv = bias[o];
            // producers: hf0 wave (t>>1), hf1 wave (2+(t>>1)); quad (t&1)
            const float* pfA = (const float*)(lds + (size_t)(t >> 1) * RGS)
                             + (t & 1) * 256;
            const float* pfB = (const float*)(lds + (size_t)(2 + (t >> 1)) * RGS)
                             + (t & 1) * 256;
#pragma unroll
            for (int r = 0; r < 4; r++) {
                int m = (lane >> 4) * 4 + r;
                if (m < 8) {
                    int n = n0 + m;
                    if (n < N) {
                        float s = pfA[r * 64 + lane] + pfB[r * 64 + lane];
                        float val = fmaxf(s + bv, 0.0f);
                        if (OUTF32) {
                            ((float*)h_out)[(size_t)n * 64 + o] = val;
                        } else {
                            ((unsigned short*)h_out)[(size_t)n * 64 + o] =
                                (unsigned short)f2bf(val);
                        }
                    }
                }
            }
        }
    }
}

extern "C" void kernel_launch(void* const* d_in, const int* in_sizes, int n_in,
                              void* d_out, int out_size, void* d_ws, size_t ws_size,
                              hipStream_t stream) {
    (void)n_in; (void)out_size; (void)ws_size;
    const float* x    = (const float*)d_in[0];
    const int*   ei   = (const int*)d_in[1];
    const float* attr = (const float*)d_in[2];
    const float* W0 = (const float*)d_in[3];
    const float* R0 = (const float*)d_in[4];
    const float* B0 = (const float*)d_in[5];
    const float* W1 = (const float*)d_in[6];
    const float* R1 = (const float*)d_in[7];
    const float* B1 = (const float*)d_in[8];
    const float* W2 = (const float*)d_in[9];
    const float* R2 = (const float*)d_in[10];
    const float* B2 = (const float*)d_in[11];
    const int N = in_sizes[0] / 3;
    const int E = in_sizes[1] / 2;

    char* ws = (char*)d_ws;
    size_t off = 0;
    auto alloc = [&](size_t bytes) {
        size_t cur = off;
        off = (off + bytes + 255) & ~(size_t)255;
        return cur;
    };
    int* row_ptr = (int*)(ws + alloc((size_t)(N + 1) * 4));
    int* count   = (int*)(ws + alloc((size_t)N * 4));
    int* cursor  = (int*)(ws + alloc((size_t)N * 4));
    int* bsum    = (int*)(ws + alloc(64 * 4));
    int* boff    = (int*)(ws + alloc(64 * 4));
    int* tot     = (int*)(ws + alloc(4));
    unsigned short* zpad = (unsigned short*)(ws + alloc(256));
    int* s_meta  = (int*)(ws + alloc((size_t)E * 4));
    unsigned short* s_wcol = (unsigned short*)(ws + alloc((size_t)E * 32 * 2));
    unsigned short* h_a  = (unsigned short*)(ws + alloc((size_t)N * 64 * 2));
    unsigned short* h_b  = (unsigned short*)(ws + alloc((size_t)N * 64 * 2));
    unsigned short* wb1  = (unsigned short*)(ws + alloc((size_t)4 * 56 * 64 * 8 * 2));
    unsigned short* wb2  = (unsigned short*)(ws + alloc((size_t)4 * 56 * 64 * 8 * 2));

    int nb = (N + 1023) / 1024;   // 49 <= 64

    hipMemsetAsync(count, 0, (size_t)N * 4, stream);
    hipMemsetAsync(zpad, 0, 256, stream);
    count_kernel<<<(E + 255) / 256, 256, 0, stream>>>(ei, count, E);
    scan_tile_kernel<<<nb, 1024, 0, stream>>>(count, row_ptr, bsum, N);
    scan_bsum_kernel<<<1, 64, 0, stream>>>(bsum, boff, tot, nb);
    scan_add_kernel<<<nb, 1024, 0, stream>>>(row_ptr, boff, tot, cursor, N);
    basis_sort_kernel<<<(E + 255) / 256, 256, 0, stream>>>(ei, attr, count, cursor,
                                                           s_meta, s_wcol, E);
    build_wb2<<<(2 * 4 * 56 * 64 + 255) / 256, 256, 0, stream>>>(W1, R1, wb1,
                                                                 W2, R2, wb2);

    layer0_kernel<<<(N + 31) / 32, 256, 0, stream>>>(x, W0, R0, B0, row_ptr,
                                                     s_meta, s_wcol, h_a, N);
    layer64_kernel<false><<<(N + 7) / 8, 512, 0, stream>>>(h_a, wb1, B1, row_ptr,
                                                           s_meta, s_wcol, zpad, h_b, N);
    layer64_kernel<true><<<(N + 7) / 8, 512, 0, stream>>>(h_b, wb2, B2, row_ptr,
                                                          s_meta, s_wcol, zpad, d_out, N);
}

// Round 16
// 384.525 us; speedup vs baseline: 1.3213x; 1.0155x over previous
//
#include <hip/hip_runtime.h>
#include <cstdint>

// SplineConv MeshEncoder: 3 layers, K=3 DIM=3 M=27, dims 3->64->64->64.
// R29 = R28 (390.5us) + layer0 latency-exposure cut:
//   layer64 2x81us; remaining ~228us is the preprocessing+layer0 half.
//   layer0 has the pre-MFMA layer64 disease: 8 serial nodes/wave x 4-deep
//   dependent chains (meta -> wcol/x) ~= 26k cy/wave -> est 60-80us.
//   (1) NPB 32->16: LDS 21.5->10.75KB, serial nodes/wave 8->4, grid x2.
//   (2) batch depth 4->8 pairs (16 edges in flight, +24 VGPR).
//   No numerics change. Everything else BYTE-IDENTICAL to R28.
//   layer64 FROZEN at R26. R16: NO LDS atomics. R14: bf16 h. R20: no
//   tr_read. R27 lesson: no single-block scans.

typedef __attribute__((ext_vector_type(8))) short short8;
typedef __attribute__((ext_vector_type(4))) float floatx4;

#define AS1 __attribute__((address_space(1)))
#define AS3 __attribute__((address_space(3)))

__device__ inline short f2bf(float f) {
    union { float f; unsigned u; } x; x.f = f;
    unsigned r = x.u + 0x7FFF + ((x.u >> 16) & 1);   // round-to-nearest-even
    return (short)(r >> 16);
}

__device__ inline float bf2f(unsigned short u) {
    union { unsigned u; float f; } x;
    x.u = ((unsigned)u) << 16;
    return x.f;
}

// ---------------- preprocessing (R10-proven) ----------------

__global__ void count_kernel(const int* __restrict__ ei, int* __restrict__ count, int E) {
    int e = blockIdx.x * blockDim.x + threadIdx.x;
    if (e < E) atomicAdd(&count[ei[E + e]], 1);
}

__global__ __launch_bounds__(1024) void scan_tile_kernel(const int* __restrict__ count,
                                                         int* __restrict__ row_ptr,
                                                         int* __restrict__ bsum, int N) {
    __shared__ int wsum[16];
    int tid = threadIdx.x, lane = tid & 63, wid = tid >> 6;
    int i = blockIdx.x * 1024 + tid;
    int v = (i < N) ? count[i] : 0;
    int incl = v;
#pragma unroll
    for (int off = 1; off < 64; off <<= 1) {
        int t = __shfl_up(incl, off, 64);
        if (lane >= off) incl += t;
    }
    if (lane == 63) wsum[wid] = incl;
    __syncthreads();
    if (tid < 16) {
        int w = wsum[tid];
#pragma unroll
        for (int off = 1; off < 16; off <<= 1) {
            int t = __shfl_up(w, off, 16);
            if ((tid & 15) >= off) w += t;
        }
        wsum[tid] = w;
    }
    __syncthreads();
    int waveoff = (wid > 0) ? wsum[wid - 1] : 0;
    if (i < N) row_ptr[i] = waveoff + incl - v;
    if (tid == 1023) bsum[blockIdx.x] = waveoff + incl;
}

__global__ __launch_bounds__(64) void scan_bsum_kernel(const int* __restrict__ bsum,
                                                       int* __restrict__ boff,
                                                       int* __restrict__ tot, int nb) {
    int tid = threadIdx.x;
    int v = (tid < nb) ? bsum[tid] : 0;
    int incl = v;
#pragma unroll
    for (int off = 1; off < 64; off <<= 1) {
        int t = __shfl_up(incl, off, 64);
        if (tid >= off) incl += t;
    }
    boff[tid] = incl - v;
    if (tid == 63) tot[0] = incl;
}

__global__ __launch_bounds__(1024) void scan_add_kernel(int* __restrict__ row_ptr,
                                                        const int* __restrict__ boff,
                                                        const int* __restrict__ tot,
                                                        int* __restrict__ cursor, int N) {
    int i = blockIdx.x * 1024 + threadIdx.x;
    if (i < N) {
        int r = row_ptr[i] + boff[blockIdx.x];
        row_ptr[i] = r;
        cursor[i] = r;
    }
    if (i == 0) row_ptr[N] = tot[0];
}

// meta = src | base<<24. s_wcol: 32 bf16 A-column per edge
// (row = base+coff(c); rows 27-31 = 0). Used by BOTH layer0 and layer64.
__global__ void basis_sort_kernel(const int* __restrict__ ei, const float* __restrict__ attr,
                                  const int* __restrict__ count, int* __restrict__ cursor,
                                  int* __restrict__ s_meta,
                                  unsigned short* __restrict__ s_wcol, int E) {
    int e = blockIdx.x * blockDim.x + threadIdx.x;
    if (e >= E) return;
    int src = ei[e];
    int dst = ei[E + e];
    float f[3]; int i0[3];
#pragma unroll
    for (int d = 0; d < 3; d++) {
        float pos = attr[e * 3 + d] * 2.0f;          // K-1 = 2
        float fl = floorf(pos);
        fl = fminf(fmaxf(fl, 0.0f), 1.0f);           // clip to [0, K-2]
        i0[d] = (int)fl;
        f[d] = pos - fl;
    }
    int base = i0[0] + 3 * i0[1] + 9 * i0[2];        // in {0,1,3,4,9,10,12,13}
    float invd = 1.0f / fmaxf((float)count[dst], 1.0f);
    int p = atomicAdd(&cursor[dst], 1);
    s_meta[p] = src | (base << 24);
    float w[8];
#pragma unroll
    for (int c = 0; c < 8; c++) {
        float ww = invd;
#pragma unroll
        for (int d = 0; d < 3; d++) {
            int off = (c >> d) & 1;
            ww *= off ? f[d] : (1.0f - f[d]);
        }
        w[c] = ww;
    }
    // A-column: zero 64B record, then scatter 8 bf16 (same line, prog order)
    unsigned short* wc = s_wcol + (size_t)p * 32;
    short8 z8 = {0, 0, 0, 0, 0, 0, 0, 0};
    *(short8*)(wc) = z8;
    *(short8*)(wc + 8) = z8;
    *(short8*)(wc + 16) = z8;
    *(short8*)(wc + 24) = z8;
#pragma unroll
    for (int c = 0; c < 8; c++) {
        int coff = (c & 1) + 3 * ((c >> 1) & 1) + 9 * (c >> 2);
        wc[base + coff] = (unsigned short)f2bf(w[c]);
    }
}

// Pre-swizzle [W(1728,64); Wr(64,64)] into bf16 MFMA B-frag order (R1-proven).
__global__ void build_wb2(const float* __restrict__ Wa, const float* __restrict__ Ra,
                          unsigned short* __restrict__ wba,
                          const float* __restrict__ Wb, const float* __restrict__ Rb,
                          unsigned short* __restrict__ wbb) {
    int idx0 = blockIdx.x * blockDim.x + threadIdx.x;   // [0, 2*4*56*64)
    int half = idx0 / (4 * 56 * 64);
    if (half >= 2) return;
    int idx = idx0 - half * (4 * 56 * 64);
    const float* W = half ? Wb : Wa;
    const float* Wr = half ? Rb : Ra;
    unsigned short* wb = half ? wbb : wba;
    int l = idx & 63;
    int c = (idx >> 6) % 56;
    int t = idx / (56 * 64);
    int q = l >> 4, o = t * 16 + (l & 15);
    short8 out;
#pragma unroll
    for (int j = 0; j < 8; j++) {
        int k = c * 32 + q * 8 + j;
        float v = (k < 1728) ? W[(size_t)k * 64 + o] : Wr[(size_t)(k - 1728) * 64 + o];
        out[j] = f2bf(v);
    }
    *(short8*)(wb + (size_t)idx * 8) = out;
}

// ---------------- layer 0 (CIN=3): dual-edge Phase A, v2 ----------------
// NPB 32->16 (LDS 10.75KB, 4 serial nodes/wave, grid x2); batch 4->8 pairs.
__global__ __launch_bounds__(256) void layer0_kernel(
    const float* __restrict__ x, const float* __restrict__ W0,
    const float* __restrict__ Wr, const float* __restrict__ bias,
    const int* __restrict__ row_ptr, const int* __restrict__ s_meta,
    const unsigned short* __restrict__ s_wcol, unsigned short* __restrict__ h_out, int N) {
    constexpr int NPB = 16, KT = 84;
    __shared__ __align__(16) float acc[NPB * 2 * KT];   // 10.75 KB (dual copies)
    int tid = threadIdx.x, lane = tid & 63, wv = tid >> 6;
    int n0 = blockIdx.x * NPB;
    for (int k = tid; k < NPB * 2 * KT; k += 256) acc[k] = 0.0f;
    __syncthreads();

    int d = lane >> 5, hl = lane & 31;
    int c = hl / 3, i = hl - c * 3;
    bool act = (hl < 24);
    int cc = act ? c : 0;
    int coff = (cc & 1) + 3 * ((cc >> 1) & 1) + 9 * (cc >> 2);   // corner offset

    for (int g2 = 0; g2 < 4; g2++) {
        int g = wv * 4 + g2;
        int n = n0 + g;
        if (n >= N) continue;
        if (lane < 3) acc[(g * 2) * KT + 81 + lane] = x[(size_t)n * 3 + lane];  // root
        int rs = row_ptr[n], re = row_ptr[n + 1];
        int npairs = (re - rs + 1) >> 1;
        float* accd = &acc[(g * 2 + d) * KT];
        for (int pb = 0; pb < npairs; pb += 8) {
            int metas[8]; float ws_[8], xs_[8];
#pragma unroll
            for (int j = 0; j < 8; j++) {            // clamp invalid -> rs (valid, w=0)
                int ej = rs + (pb + j) * 2 + d;
                bool v = (pb + j < npairs) && (ej < re);
                int ec = v ? ej : rs;
                metas[j] = s_meta[ec];
                int base = (metas[j] >> 24) & 0xF;
                float wv_ = bf2f(s_wcol[(size_t)ec * 32 + base + coff]);
                ws_[j] = v ? wv_ : 0.0f;
            }
#pragma unroll
            for (int j = 0; j < 8; j++)
                xs_[j] = x[(size_t)(metas[j] & 0xFFFFFF) * 3 + i];
#pragma unroll
            for (int j = 0; j < 8; j++) {
                int kidx = ((metas[j] >> 24) & 0xF) + coff;
                if (act) accd[kidx * 3 + i] += ws_[j] * xs_[j];
            }
        }
    }
    __syncthreads();

    // Phase B: o = lane, W in 84 registers; sum the dual acc copies.
    int o = lane;
    float wreg[KT];
#pragma unroll
    for (int k = 0; k < KT; k++)
        wreg[k] = (k < 81) ? W0[k * 64 + o] : Wr[(k - 81) * 64 + o];
    float bv = bias[o];
    for (int g = wv; g < NPB; g += 4) {
        int n = n0 + g;
        if (n >= N) break;
        float s = bv;
#pragma unroll
        for (int k4 = 0; k4 < KT; k4 += 4) {
            floatx4 a0 = *(const floatx4*)&acc[(g * 2) * KT + k4];
            floatx4 a1 = *(const floatx4*)&acc[(g * 2 + 1) * KT + k4];
            s += (a0.x + a1.x) * wreg[k4] + (a0.y + a1.y) * wreg[k4 + 1]
               + (a0.z + a1.z) * wreg[k4 + 2] + (a0.w + a1.w) * wreg[k4 + 3];
        }
        h_out[(size_t)n * 64 + o] = (unsigned short)f2bf(fmaxf(s, 0.0f));
    }
}

// ---------------- 64-ch layers: MFMA Phase A (v6, wcol A-columns) ----------------
// BYTE-IDENTICAL to R26 (FROZEN).
template <bool OUTF32>
__global__ __launch_bounds__(512, 4) void layer64_kernel(
    const unsigned short* __restrict__ h_in, const unsigned short* __restrict__ wb,
    const float* __restrict__ bias, const int* __restrict__ row_ptr,
    const int* __restrict__ s_meta, const unsigned short* __restrict__ s_wcol,
    const unsigned short* __restrict__ zpad, void* __restrict__ h_out, int N) {
    constexpr int NPB = 8;
    constexpr int RGS = 3216;
    __shared__ __align__(16) unsigned short lds[NPB * RGS];   // 51,456 B
    int tid = threadIdx.x, lane = tid & 63;
    int wvu = __builtin_amdgcn_readfirstlane(tid >> 6);   // uniform wave id 0..7
    int n0 = blockIdx.x * NPB;
    int srow = lane & 15, sgrp = lane >> 4;

    unsigned short* reg = &lds[(size_t)wvu * RGS];
    unsigned short* featL = reg;                     // 4096 B
    unsigned short* wcolL = reg + 2048;              // 2048 B (32 edges x 32 bf16)
    int* metaL = (int*)(reg + 3072);                 // 256 B

// stage wcol for 32 window-local edges starting at CB (clamped -> zpad)
#define STAGE_WCOL(CB) do { \
    _Pragma("unroll") for (int k = 0; k < 2; k++) { \
        int el = (CB) + k * 16 + (lane >> 2); \
        const unsigned short* srcp = (el < dw) \
            ? s_wcol + (size_t)(rs + wbo + el) * 32 + (lane & 3) * 8 \
            : zpad + (lane & 3) * 8; \
        __builtin_amdgcn_global_load_lds((const AS1 unsigned int*)srcp, \
            (AS3 unsigned int*)(wcolL + k * 512), 16, 0, 0); \
    } \
} while (0)

    // ---- Phase A: acc(27x64) = Wbasis(27 x deg) X(deg x 64) via MFMA ----
    {
        int n = n0 + wvu;
        if (n >= N) {   // tail hygiene: zero the row so Phase B sees no stale LDS
            for (int k = lane; k < 1792; k += 64) reg[k] = 0;
        } else {
            // zero feat once: unstaged slots stay finite (af=0 covers them)
            {
                short8 z = {0, 0, 0, 0, 0, 0, 0, 0};
#pragma unroll
                for (int s = 0; s < 4; s++)
                    *(short8*)(featL + lane * 8 + s * 512) = z;
            }
            floatx4 facc[2][4];
#pragma unroll
            for (int mt = 0; mt < 2; mt++)
#pragma unroll
                for (int nt = 0; nt < 4; nt++)
                    facc[mt][nt] = (floatx4){0.0f, 0.0f, 0.0f, 0.0f};

            int rs = row_ptr[n], re = row_ptr[n + 1];
            int deg = re - rs;
            for (int wbo = 0; wbo < deg; wbo += 64) {
                int dw = deg - wbo;
                // ---- stage window: meta (64x4B) + wcol chunk0 ----
                __builtin_amdgcn_global_load_lds(
                    (const AS1 unsigned int*)(s_meta + rs + wbo + lane),
                    (AS3 unsigned int*)metaL, 4, 0, 0);
                STAGE_WCOL(0);
                asm volatile("s_waitcnt vmcnt(0)" ::: "memory");   // meta+wcol0 landed
                int vmax = (dw < 64 ? dw : 64) - 1;
                for (int ch2 = 0; ch2 < 2; ch2++) {
                    int cb = ch2 * 32;
                    if (cb >= dw) break;
                    // ---- stage features: exact-count w16 gloads, swizzled src ----
                    //   lane L, instr i: edge el = cb + i*8 + (L>>3),
                    //   granule c3 = (L&7) ^ (i<<1)  (linear dest =>
                    //   granule G = e*8 + (c3 ^ ((e>>3)<<1)))
                    int nsl = dw - cb; if (nsl > 32) nsl = 32;
                    int ngl = (nsl + 7) >> 3;
                    for (int i = 0; i < ngl; i++) {
                        int el = cb + i * 8 + (lane >> 3);
                        if (el > vmax) el = vmax;
                        int ms = metaL[el] & 0xFFFFFF;
                        int c3 = (lane & 7) ^ (i << 1);
                        const unsigned short* srcp = h_in + (size_t)ms * 64 + c3 * 8;
                        __builtin_amdgcn_global_load_lds(
                            (const AS1 unsigned int*)srcp,
                            (AS3 unsigned int*)(featL + i * 512), 16, 0, 0);
                    }
                    // ---- A-frags: 16 ds_read_u16 from wcolL (imm offsets) ----
                    short8 af0, af1;
                    {
                        const unsigned short* wrp = wcolL + (8 * sgrp) * 32 + srow;
#pragma unroll
                        for (int j = 0; j < 8; j++) {
                            af0[j] = (short)wrp[j * 32];
                            af1[j] = (short)wrp[j * 32 + 16];
                        }
                    }
                    // chunk1's wcol reload (single-buffered): only after the
                    // A-build ds_reads completed (WAR guard).
                    if (ch2 == 0 && dw > 32) {
                        asm volatile("s_waitcnt lgkmcnt(0)" ::: "memory");
                        __builtin_amdgcn_sched_barrier(0);
                        STAGE_WCOL(32);
                    }
                    asm volatile("s_waitcnt vmcnt(0)" ::: "memory");   // feat landed
                    // ---- B-frags from swizzled feat + 8 MFMA ----
#pragma unroll
                    for (int nt = 0; nt < 4; nt++) {
                        short8 bn;
#pragma unroll
                        for (int jj = 0; jj < 8; jj++) {
                            int e = sgrp * 8 + jj;           // chunk-local
                            int g = e * 8 + (((nt * 2) + (srow >> 3)) ^ (sgrp << 1));
                            bn[jj] = (short)featL[g * 8 + (srow & 7)];
                        }
                        facc[0][nt] = __builtin_amdgcn_mfma_f32_16x16x32_bf16(
                            af0, bn, facc[0][nt], 0, 0, 0);
                        facc[1][nt] = __builtin_amdgcn_mfma_f32_16x16x32_bf16(
                            af1, bn, facc[1][nt], 0, 0, 0);
                    }
                }
            }
            // ---- C write (layout: col=srow+16nt, row=sgrp*4+r+16mt) ----
#pragma unroll
            for (int mt = 0; mt < 2; mt++)
#pragma unroll
                for (int nt = 0; nt < 4; nt++)
#pragma unroll
                    for (int r = 0; r < 4; r++) {
                        int mrow = mt * 16 + sgrp * 4 + r;
                        if (mrow < 27)
                            reg[mrow * 64 + nt * 16 + srow] =
                                (unsigned short)f2bf(facc[mt][nt][r]);
                    }
            reg[1728 + lane] = h_in[(size_t)n * 64 + lane];   // root row (bf16)
        }
    }
#undef STAGE_WCOL
    __syncthreads();

    // ---- Phase B: 4 waves, each 2 col-groups per A-read ----
    {
        floatx4 f0 = {0.0f, 0.0f, 0.0f, 0.0f};
        floatx4 f1 = {0.0f, 0.0f, 0.0f, 0.0f};
        if (wvu < 4) {
            int hf = wvu >> 1;                   // K half: c in [hf*28, hf*28+28)
            int tp = wvu & 1;                    // col-group pair: nt = 2tp, 2tp+1
            const unsigned short* ap = lds + (size_t)(lane & 7) * RGS + ((lane >> 4) * 8);
            const unsigned short* wbp0 = wb + ((size_t)((tp * 2) * 56) * 64 + lane) * 8;
            const unsigned short* wbp1 = wb + ((size_t)((tp * 2 + 1) * 56) * 64 + lane) * 8;
#pragma unroll
            for (int ci = 0; ci < 28; ci++) {
                int c = hf * 28 + ci;
                short8 af = *(const short8*)(ap + c * 32);
                short8 b0 = *(const short8*)(wbp0 + (size_t)c * 64 * 8);
                short8 b1 = *(const short8*)(wbp1 + (size_t)c * 64 * 8);
                f0 = __builtin_amdgcn_mfma_f32_16x16x32_bf16(af, b0, f0, 0, 0, 0);
                f1 = __builtin_amdgcn_mfma_f32_16x16x32_bf16(af, b1, f1, 0, 0, 0);
            }
        }
        __syncthreads();               // all MFMA reads of lds complete
        if (wvu < 4) {
            float* pfw = (float*)(lds + (size_t)wvu * RGS);
#pragma unroll
            for (int r = 0; r < 4; r++) {
                pfw[r * 64 + lane] = f0[r];
                pfw[256 + r * 64 + lane] = f1[r];
            }
        }
        __syncthreads();
        if (wvu < 4) {
            int t = wvu;                         // output col group t
            int o = t * 16 + (lane & 15);
            float bv = bias[o];
            // producers: hf0 wave (t>>1), hf1 wave (2+(t>>1)); quad (t&1)
            const float* pfA = (const float*)(lds + (size_t)(t >> 1) * RGS)
                             + (t & 1) * 256;
            const float* pfB = (const float*)(lds + (size_t)(2 + (t >> 1)) * RGS)
                             + (t & 1) * 256;
#pragma unroll
            for (int r = 0; r < 4; r++) {
                int m = (lane >> 4) * 4 + r;
                if (m < 8) {
                    int n = n0 + m;
                    if (n < N) {
                        float s = pfA[r * 64 + lane] + pfB[r * 64 + lane];
                        float val = fmaxf(s + bv, 0.0f);
                        if (OUTF32) {
                            ((float*)h_out)[(size_t)n * 64 + o] = val;
                        } else {
                            ((unsigned short*)h_out)[(size_t)n * 64 + o] =
                                (unsigned short)f2bf(val);
                        }
                    }
                }
            }
        }
    }
}

extern "C" void kernel_launch(void* const* d_in, const int* in_sizes, int n_in,
                              void* d_out, int out_size, void* d_ws, size_t ws_size,
                              hipStream_t stream) {
    (void)n_in; (void)out_size; (void)ws_size;
    const float* x    = (const float*)d_in[0];
    const int*   ei   = (const int*)d_in[1];
    const float* attr = (const float*)d_in[2];
    const float* W0 = (const float*)d_in[3];
    const float* R0 = (const float*)d_in[4];
    const float* B0 = (const float*)d_in[5];
    const float* W1 = (const float*)d_in[6];
    const float* R1 = (const float*)d_in[7];
    const float* B1 = (const float*)d_in[8];
    const float* W2 = (const float*)d_in[9];
    const float* R2 = (const float*)d_in[10];
    const float* B2 = (const float*)d_in[11];
    const int N = in_sizes[0] / 3;
    const int E = in_sizes[1] / 2;

    char* ws = (char*)d_ws;
    size_t off = 0;
    auto alloc = [&](size_t bytes) {
        size_t cur = off;
        off = (off + bytes + 255) & ~(size_t)255;
        return cur;
    };
    int* row_ptr = (int*)(ws + alloc((size_t)(N + 1) * 4));
    int* count   = (int*)(ws + alloc((size_t)N * 4));
    int* cursor  = (int*)(ws + alloc((size_t)N * 4));
    int* bsum    = (int*)(ws + alloc(64 * 4));
    int* boff    = (int*)(ws + alloc(64 * 4));
    int* tot     = (int*)(ws + alloc(4));
    unsigned short* zpad = (unsigned short*)(ws + alloc(256));
    int* s_meta  = (int*)(ws + alloc((size_t)E * 4));
    unsigned short* s_wcol = (unsigned short*)(ws + alloc((size_t)E * 32 * 2));
    unsigned short* h_a  = (unsigned short*)(ws + alloc((size_t)N * 64 * 2));
    unsigned short* h_b  = (unsigned short*)(ws + alloc((size_t)N * 64 * 2));
    unsigned short* wb1  = (unsigned short*)(ws + alloc((size_t)4 * 56 * 64 * 8 * 2));
    unsigned short* wb2  = (unsigned short*)(ws + alloc((size_t)4 * 56 * 64 * 8 * 2));

    int nb = (N + 1023) / 1024;   // 49 <= 64

    hipMemsetAsync(count, 0, (size_t)N * 4, stream);
    hipMemsetAsync(zpad, 0, 256, stream);
    count_kernel<<<(E + 255) / 256, 256, 0, stream>>>(ei, count, E);
    scan_tile_kernel<<<nb, 1024, 0, stream>>>(count, row_ptr, bsum, N);
    scan_bsum_kernel<<<1, 64, 0, stream>>>(bsum, boff, tot, nb);
    scan_add_kernel<<<nb, 1024, 0, stream>>>(row_ptr, boff, tot, cursor, N);
    basis_sort_kernel<<<(E + 255) / 256, 256, 0, stream>>>(ei, attr, count, cursor,
                                                           s_meta, s_wcol, E);
    build_wb2<<<(2 * 4 * 56 * 64 + 255) / 256, 256, 0, stream>>>(W1, R1, wb1,
                                                                 W2, R2, wb2);

    layer0_kernel<<<(N + 15) / 16, 256, 0, stream>>>(x, W0, R0, B0, row_ptr,
                                                     s_meta, s_wcol, h_a, N);
    layer64_kernel<false><<<(N + 7) / 8, 512, 0, stream>>>(h_a, wb1, B1, row_ptr,
                                                           s_meta, s_wcol, zpad, h_b, N);
    layer64_kernel<true><<<(N + 7) / 8, 512, 0, stream>>>(h_b, wb2, B2, row_ptr,
                                                          s_meta, s_wcol, zpad, d_out, N);
}